// Round 1
// baseline (154.988 us; speedup 1.0000x reference)
//
#include <hip/hip_runtime.h>

#define B_ 512
#define S_ 4
#define K_ 912
#define R_ 8
#define D_ 912
#define NCODE 1824
#define BSK (B_*S_*K_)   /* 1867776 */
#define BP_ITERS 10

// Smith's algorithm complex division (matches LAPACK cladiv)
__device__ __forceinline__ void cdivf(float xr, float xi, float cr, float ci,
                                      float& rr, float& ri) {
  if (fabsf(ci) <= fabsf(cr)) {
    float e = ci / cr;
    float f = cr + ci * e;
    rr = (xr + xi * e) / f;
    ri = (xi - xr * e) / f;
  } else {
    float e = cr / ci;
    float f = cr * e + ci;
    rr = (xr * e + xi) / f;
    ri = (xi * e - xr) / f;
  }
}

__global__ __launch_bounds__(256) void mmse_llr_kernel(
    const int* __restrict__ bbits, const float* __restrict__ hre,
    const float* __restrict__ him, const float* __restrict__ nre,
    const float* __restrict__ nim, const int* __restrict__ ebno,
    float* __restrict__ outf) {
#pragma clang fp contract(off)
  int t = blockIdx.x * blockDim.x + threadIdx.x;
  if (t >= B_ * D_) return;
  int b = t / D_;
  int d = t - b * D_;

  int ei = ebno[0];
  float ef = (ei >= -100 && ei <= 100) ? (float)ei : __int_as_float(ei);
  double no_d = pow(10.0, -(double)ef / 10.0);
  float no_f = (float)no_d;
  float nscale = (float)sqrt(no_d * 0.5);
  const float INV2 = 0.70710678118654752440f;

  // --- QPSK symbols for the 4 streams at subcarrier d ---
  float xr[S_], xq[S_];
  int k2 = 2 * d;
#pragma unroll
  for (int s = 0; s < S_; ++s) {
    const int* bb = bbits + (b * S_ + s) * K_;
    int c0, c1;
    if (k2 < K_) {
      c0 = bb[k2];
      c1 = bb[k2 + 1];
    } else {
      int j0 = k2 - K_, j1 = k2 + 1 - K_;
      int j0a = j0 - 7;   if (j0a < 0) j0a += K_;
      int j0b = j0 - 150; if (j0b < 0) j0b += K_;
      c0 = (bb[j0] + bb[j0a] + bb[j0b]) & 1;
      int j1a = j1 - 7;   if (j1a < 0) j1a += K_;
      int j1b = j1 - 150; if (j1b < 0) j1b += K_;
      c1 = (bb[j1] + bb[j1a] + bb[j1b]) & 1;
    }
    xr[s] = (1.0f - 2.0f * (float)c0) * INV2;
    xq[s] = (1.0f - 2.0f * (float)c1) * INV2;
  }

  // --- load H (scaled by 1/sqrt2) ---
  float Hr[R_][S_], Hi[R_][S_];
  const float* hr0 = hre + (size_t)t * (R_ * S_);
  const float* hi0 = him + (size_t)t * (R_ * S_);
#pragma unroll
  for (int r = 0; r < R_; ++r)
#pragma unroll
    for (int s = 0; s < S_; ++s) {
      Hr[r][s] = hr0[r * S_ + s] * INV2;
      Hi[r][s] = hi0[r * S_ + s] * INV2;
    }

  // --- y = H x + noise ---
  float yr[R_], yi[R_];
#pragma unroll
  for (int r = 0; r < R_; ++r) {
    float ar = 0.f, ai = 0.f;
#pragma unroll
    for (int s = 0; s < S_; ++s) {
      ar += Hr[r][s] * xr[s] - Hi[r][s] * xq[s];
      ai += Hr[r][s] * xq[s] + Hi[r][s] * xr[s];
    }
    yr[r] = ar + nre[(size_t)t * R_ + r] * nscale;
    yi[r] = ai + nim[(size_t)t * R_ + r] * nscale;
  }

  // --- A = H^H H + no*I (4x4 complex) ---
  float Ar[S_][S_], Ai[S_][S_];
#pragma unroll
  for (int s = 0; s < S_; ++s)
#pragma unroll
    for (int u = 0; u < S_; ++u) {
      float ar = 0.f, ai = 0.f;
#pragma unroll
      for (int r = 0; r < R_; ++r) {
        ar += Hr[r][s] * Hr[r][u] + Hi[r][s] * Hi[r][u];
        ai += Hr[r][s] * Hi[r][u] - Hi[r][s] * Hr[r][u];
      }
      Ar[s][u] = ar;
      Ai[s][u] = ai;
    }
#pragma unroll
  for (int s = 0; s < S_; ++s) Ar[s][s] += no_f;

  // --- LU with partial pivoting (cabs1 = |re|+|im|, LAPACK-style) ---
  int piv[S_];
#pragma unroll
  for (int j = 0; j < S_; ++j) {
    int p = j;
    float best = fabsf(Ar[j][j]) + fabsf(Ai[j][j]);
#pragma unroll
    for (int i = j + 1; i < S_; ++i) {
      float v = fabsf(Ar[i][j]) + fabsf(Ai[i][j]);
      if (v > best) { best = v; p = i; }
    }
    piv[j] = p;
    // conditional row swaps with constant indices (keep arrays in regs)
#pragma unroll
    for (int q = j + 1; q < S_; ++q) {
      bool sw = (p == q);
#pragma unroll
      for (int k = 0; k < S_; ++k) {
        float t0 = sw ? Ar[q][k] : Ar[j][k];
        float t1 = sw ? Ar[j][k] : Ar[q][k];
        Ar[j][k] = t0; Ar[q][k] = t1;
        float u0 = sw ? Ai[q][k] : Ai[j][k];
        float u1 = sw ? Ai[j][k] : Ai[q][k];
        Ai[j][k] = u0; Ai[q][k] = u1;
      }
    }
    float rr, ri;
    cdivf(1.f, 0.f, Ar[j][j], Ai[j][j], rr, ri);
#pragma unroll
    for (int i = j + 1; i < S_; ++i) {
      float mr = Ar[i][j] * rr - Ai[i][j] * ri;
      float mi = Ar[i][j] * ri + Ai[i][j] * rr;
      Ar[i][j] = mr;
      Ai[i][j] = mi;
    }
#pragma unroll
    for (int i = j + 1; i < S_; ++i)
#pragma unroll
      for (int k = j + 1; k < S_; ++k) {
        Ar[i][k] -= Ar[i][j] * Ar[j][k] - Ai[i][j] * Ai[j][k];
        Ai[i][k] -= Ar[i][j] * Ai[j][k] + Ai[i][j] * Ar[j][k];
      }
  }

  // --- solve A G = H^H column by column; accumulate z and dgg ---
  float zr[S_] = {0.f, 0.f, 0.f, 0.f};
  float zq[S_] = {0.f, 0.f, 0.f, 0.f};
  float dgg[S_] = {0.f, 0.f, 0.f, 0.f};
#pragma unroll
  for (int r = 0; r < R_; ++r) {
    float br[S_], bq[S_];
#pragma unroll
    for (int s = 0; s < S_; ++s) { br[s] = Hr[r][s]; bq[s] = -Hi[r][s]; }
    // apply pivots
#pragma unroll
    for (int j = 0; j < S_; ++j) {
      int p = piv[j];
#pragma unroll
      for (int q = j + 1; q < S_; ++q) {
        bool sw = (p == q);
        float t0 = sw ? br[q] : br[j];
        float t1 = sw ? br[j] : br[q];
        br[j] = t0; br[q] = t1;
        float u0 = sw ? bq[q] : bq[j];
        float u1 = sw ? bq[j] : bq[q];
        bq[j] = u0; bq[q] = u1;
      }
    }
    // forward solve (unit lower)
#pragma unroll
    for (int i = 1; i < S_; ++i)
#pragma unroll
      for (int j = 0; j < i; ++j) {
        br[i] -= Ar[i][j] * br[j] - Ai[i][j] * bq[j];
        bq[i] -= Ar[i][j] * bq[j] + Ai[i][j] * br[j];
      }
    // back solve (divide by diagonal)
#pragma unroll
    for (int i = S_ - 1; i >= 0; --i) {
#pragma unroll
      for (int j = i + 1; j < S_; ++j) {
        br[i] -= Ar[i][j] * br[j] - Ai[i][j] * bq[j];
        bq[i] -= Ar[i][j] * bq[j] + Ai[i][j] * br[j];
      }
      float qr2, qi2;
      cdivf(br[i], bq[i], Ar[i][i], Ai[i][i], qr2, qi2);
      br[i] = qr2;
      bq[i] = qi2;
    }
    // accumulate z += G[:,r]*y[r], dgg += Re(G[:,r]*h[r,:])
#pragma unroll
    for (int s = 0; s < S_; ++s) {
      zr[s] += br[s] * yr[r] - bq[s] * yi[r];
      zq[s] += br[s] * yi[r] + bq[s] * yr[r];
      dgg[s] += br[s] * Hr[r][s] - bq[s] * Hi[r][s];
    }
  }

  // --- LLRs (store L = -llr, overlaid on d_out as floats) ---
#pragma unroll
  for (int s = 0; s < S_; ++s) {
    float dg = fminf(fmaxf(dgg[s], 1e-6f), (float)(1.0 - 1e-6));
    float xhr = zr[s] / dg;
    float xhi = zq[s] / dg;
    float noe = (1.0f - dg) / dg;
    float sc = -2.8284270763397217f / noe;  // -2*float32(sqrt(2)) / no_eff
    float l0 = -(sc * xhr);
    float l1 = -(sc * xhi);
    size_t w = (size_t)(b * S_ + s);
    if (k2 < K_) {
      outf[w * K_ + k2]     = l0;
      outf[w * K_ + k2 + 1] = l1;
    } else {
      outf[(size_t)BSK + w * K_ + (k2 - K_)]     = l0;
      outf[(size_t)BSK + w * K_ + (k2 - K_) + 1] = l1;
    }
  }
}

__global__ __launch_bounds__(256) void bp_kernel(const int* __restrict__ bbits,
                                                 int* __restrict__ out) {
#pragma clang fp contract(off)
  __shared__ float Ls[NCODE];
  __shared__ float tot[NCODE];
  __shared__ float c2v[4][K_];
  int w = blockIdx.x;
  int tid = threadIdx.x;
  const float* outf = (const float*)out;

  for (int n = tid; n < K_; n += 256) {
    Ls[n]      = outf[(size_t)w * K_ + n];
    Ls[K_ + n] = outf[(size_t)BSK + (size_t)w * K_ + n];
  }
  for (int n = tid; n < 4 * K_; n += 256) ((float*)c2v)[n] = 0.f;
  __syncthreads();

  for (int it = 0; it < BP_ITERS; ++it) {
    // phase A: tot[n] = L[n] + sum of incident c2v (gather form)
    for (int n = tid; n < NCODE; n += 256) {
      float e;
      if (n < K_) {
        int ca = n + 7;   if (ca >= K_) ca -= K_;
        int cb = n + 150; if (cb >= K_) cb -= K_;
        e = c2v[0][n] + c2v[1][ca] + c2v[2][cb];
      } else {
        e = c2v[3][n - K_];
      }
      tot[n] = Ls[n] + e;
    }
    __syncthreads();
    // phase B: per-check min-sum update
    for (int c = tid; c < K_; c += 256) {
      int v1 = c - 7;   if (v1 < 0) v1 += K_;
      int v2 = c - 150; if (v2 < 0) v2 += K_;
      float m0 = tot[c]       - c2v[0][c];
      float m1 = tot[v1]      - c2v[1][c];
      float m2 = tot[v2]      - c2v[2][c];
      float m3 = tot[K_ + c]  - c2v[3][c];
      float a0 = fabsf(m0), a1 = fabsf(m1), a2 = fabsf(m2), a3 = fabsf(m3);
      float min1 = a0, min2 = __builtin_inff();
      int am = 0;
      if (a1 < min1) { min2 = min1; min1 = a1; am = 1; } else if (a1 < min2) min2 = a1;
      if (a2 < min1) { min2 = min1; min1 = a2; am = 2; } else if (a2 < min2) min2 = a2;
      if (a3 < min1) { min2 = min1; min1 = a3; am = 3; } else if (a3 < min2) min2 = a3;
      float s0 = (m0 < 0.f) ? -1.f : 1.f;
      float s1 = (m1 < 0.f) ? -1.f : 1.f;
      float s2 = (m2 < 0.f) ? -1.f : 1.f;
      float s3 = (m3 < 0.f) ? -1.f : 1.f;
      float sp = s0 * s1 * s2 * s3;
      c2v[0][c] = (sp * s0) * ((am == 0) ? min2 : min1);
      c2v[1][c] = (sp * s1) * ((am == 1) ? min2 : min1);
      c2v[2][c] = (sp * s2) * ((am == 2) ? min2 : min1);
      c2v[3][c] = (sp * s3) * ((am == 3) ? min2 : min1);
    }
    __syncthreads();
  }

  // final: hard decisions on info bits + copy b_bits to first half
  for (int k = tid; k < K_; k += 256) {
    int ca = k + 7;   if (ca >= K_) ca -= K_;
    int cb = k + 150; if (cb >= K_) cb -= K_;
    float ttt = Ls[k] + c2v[0][k] + c2v[1][ca] + c2v[2][cb];
    out[(size_t)BSK + (size_t)w * K_ + k] = (ttt < 0.f) ? 1 : 0;
    out[(size_t)w * K_ + k] = bbits[(size_t)w * K_ + k];
  }
}

extern "C" void kernel_launch(void* const* d_in, const int* in_sizes, int n_in,
                              void* d_out, int out_size, void* d_ws, size_t ws_size,
                              hipStream_t stream) {
  const int*   b_bits = (const int*)d_in[0];
  const float* h_real = (const float*)d_in[1];
  const float* h_imag = (const float*)d_in[2];
  const float* n_real = (const float*)d_in[3];
  const float* n_imag = (const float*)d_in[4];
  const int*   ebno   = (const int*)d_in[5];
  int* out = (int*)d_out;

  // Stage 1: per-(b,d) LMMSE + LLR, writes L (floats) overlaid on d_out
  mmse_llr_kernel<<<(B_ * D_ + 255) / 256, 256, 0, stream>>>(
      b_bits, h_real, h_imag, n_real, n_imag, ebno, (float*)d_out);
  // Stage 2: per-codeword min-sum BP, converts overlay into int outputs
  bp_kernel<<<B_ * S_, 256, 0, stream>>>(b_bits, out);
}

// Round 2
// 95.966 us; speedup vs baseline: 1.6150x; 1.6150x over previous
//
#include <hip/hip_runtime.h>

#define B_ 512
#define S_ 4
#define K_ 912
#define R_ 8
#define D_ 912
#define NCODE 1824
#define BSK (B_*S_*K_)   /* 1867776 */
#define BP_ITERS 10

// one-thread kernel: compute no / noise-scale once (fp64 pow off the hot path)
__global__ void setup_kernel(const int* __restrict__ ebno, float* __restrict__ cst) {
  int ei = ebno[0];
  float ef = (ei >= -100 && ei <= 100) ? (float)ei : __int_as_float(ei);
  double no_d = pow(10.0, -(double)ef / 10.0);
  cst[0] = (float)no_d;
  cst[1] = (float)sqrt(no_d * 0.5);
}

__global__ __launch_bounds__(256) void mmse_llr_kernel(
    const int* __restrict__ bbits, const float* __restrict__ hre,
    const float* __restrict__ him, const float* __restrict__ nre,
    const float* __restrict__ nim, const float* __restrict__ cst,
    float* __restrict__ outf) {
#pragma clang fp contract(off)
  int t = blockIdx.x * blockDim.x + threadIdx.x;
  if (t >= B_ * D_) return;
  int b = t / D_;
  int d = t - b * D_;

  const float no_f = cst[0];
  const float nscale = cst[1];
  const float INV2 = 0.70710678118654752440f;

  // --- QPSK symbols for the 4 streams at subcarrier d ---
  float xr[S_], xq[S_];
  int k2 = 2 * d;
#pragma unroll
  for (int s = 0; s < S_; ++s) {
    const int* bb = bbits + (b * S_ + s) * K_;
    int c0, c1;
    if (k2 < K_) {
      c0 = bb[k2];
      c1 = bb[k2 + 1];
    } else {
      int j0 = k2 - K_, j1 = k2 + 1 - K_;
      int j0a = j0 - 7;   if (j0a < 0) j0a += K_;
      int j0b = j0 - 150; if (j0b < 0) j0b += K_;
      c0 = (bb[j0] + bb[j0a] + bb[j0b]) & 1;
      int j1a = j1 - 7;   if (j1a < 0) j1a += K_;
      int j1b = j1 - 150; if (j1b < 0) j1b += K_;
      c1 = (bb[j1] + bb[j1a] + bb[j1b]) & 1;
    }
    xr[s] = (1.0f - 2.0f * (float)c0) * INV2;
    xq[s] = (1.0f - 2.0f * (float)c1) * INV2;
  }

  // --- stream over r: build y_r, accumulate A (lower tri) and w = H^H y ---
  const float4* hr4 = reinterpret_cast<const float4*>(hre + (size_t)t * 32);
  const float4* hi4 = reinterpret_cast<const float4*>(him + (size_t)t * 32);
  const float4* nr4 = reinterpret_cast<const float4*>(nre + (size_t)t * 8);
  const float4* ni4 = reinterpret_cast<const float4*>(nim + (size_t)t * 8);
  float nrv[8], niv[8];
  {
    float4 a = nr4[0], b2 = nr4[1];
    nrv[0]=a.x; nrv[1]=a.y; nrv[2]=a.z; nrv[3]=a.w;
    nrv[4]=b2.x; nrv[5]=b2.y; nrv[6]=b2.z; nrv[7]=b2.w;
    float4 c = ni4[0], d2 = ni4[1];
    niv[0]=c.x; niv[1]=c.y; niv[2]=c.z; niv[3]=c.w;
    niv[4]=d2.x; niv[5]=d2.y; niv[6]=d2.z; niv[7]=d2.w;
  }

  float Ad0=0.f, Ad1=0.f, Ad2=0.f, Ad3=0.f;
  float A10r=0.f,A10i=0.f,A20r=0.f,A20i=0.f,A21r=0.f,A21i=0.f;
  float A30r=0.f,A30i=0.f,A31r=0.f,A31i=0.f,A32r=0.f,A32i=0.f;
  float w0r=0.f,w0i=0.f,w1r=0.f,w1i=0.f,w2r=0.f,w2i=0.f,w3r=0.f,w3i=0.f;

#pragma unroll
  for (int r = 0; r < R_; ++r) {
    float4 h4r = hr4[r], h4i = hi4[r];
    float hr0=h4r.x*INV2, hr1=h4r.y*INV2, hr2=h4r.z*INV2, hr3=h4r.w*INV2;
    float hi0=h4i.x*INV2, hi1=h4i.y*INV2, hi2=h4i.z*INV2, hi3=h4i.w*INV2;
    // y_r = sum_s h[r][s]*x[s]  (+ noise)
    float yr = 0.f, yi = 0.f;
    yr += hr0*xr[0] - hi0*xq[0]; yi += hr0*xq[0] + hi0*xr[0];
    yr += hr1*xr[1] - hi1*xq[1]; yi += hr1*xq[1] + hi1*xr[1];
    yr += hr2*xr[2] - hi2*xq[2]; yi += hr2*xq[2] + hi2*xr[2];
    yr += hr3*xr[3] - hi3*xq[3]; yi += hr3*xq[3] + hi3*xr[3];
    yr += nrv[r]*nscale; yi += niv[r]*nscale;
    // A[i][j] += conj(h_ri)*h_rj (lower triangle), diagonal real
    Ad0 += hr0*hr0 + hi0*hi0;
    Ad1 += hr1*hr1 + hi1*hi1;
    Ad2 += hr2*hr2 + hi2*hi2;
    Ad3 += hr3*hr3 + hi3*hi3;
    A10r += hr1*hr0 + hi1*hi0;  A10i += hr1*hi0 - hi1*hr0;
    A20r += hr2*hr0 + hi2*hi0;  A20i += hr2*hi0 - hi2*hr0;
    A21r += hr2*hr1 + hi2*hi1;  A21i += hr2*hi1 - hi2*hr1;
    A30r += hr3*hr0 + hi3*hi0;  A30i += hr3*hi0 - hi3*hr0;
    A31r += hr3*hr1 + hi3*hi1;  A31i += hr3*hi1 - hi3*hr1;
    A32r += hr3*hr2 + hi3*hi2;  A32i += hr3*hi2 - hi3*hr2;
    // w[s] += conj(h_rs) * y_r
    w0r += hr0*yr + hi0*yi;  w0i += hr0*yi - hi0*yr;
    w1r += hr1*yr + hi1*yi;  w1i += hr1*yi - hi1*yr;
    w2r += hr2*yr + hi2*yi;  w2i += hr2*yi - hi2*yr;
    w3r += hr3*yr + hi3*yi;  w3i += hr3*yi - hi3*yr;
  }

  // --- LDL^H factorization (A is HPD: lambda_min >= no ~ 0.1) ---
  float Dv0 = Ad0 + no_f;
  float iD0 = 1.0f / Dv0;
  float L10r = A10r*iD0, L10i = A10i*iD0;
  float L20r = A20r*iD0, L20i = A20i*iD0;
  float L30r = A30r*iD0, L30i = A30i*iD0;
  float Dv1 = Ad1 + no_f - (L10r*L10r + L10i*L10i)*Dv0;
  float iD1 = 1.0f / Dv1;
  float t21r = A21r - (L20r*L10r + L20i*L10i)*Dv0;
  float t21i = A21i - (L20i*L10r - L20r*L10i)*Dv0;
  float L21r = t21r*iD1, L21i = t21i*iD1;
  float t31r = A31r - (L30r*L10r + L30i*L10i)*Dv0;
  float t31i = A31i - (L30i*L10r - L30r*L10i)*Dv0;
  float L31r = t31r*iD1, L31i = t31i*iD1;
  float Dv2 = Ad2 + no_f - (L20r*L20r + L20i*L20i)*Dv0 - (L21r*L21r + L21i*L21i)*Dv1;
  float iD2 = 1.0f / Dv2;
  float t32r = A32r - (L30r*L20r + L30i*L20i)*Dv0 - (L31r*L21r + L31i*L21i)*Dv1;
  float t32i = A32i - (L30i*L20r - L30r*L20i)*Dv0 - (L31i*L21r - L31r*L21i)*Dv1;
  float L32r = t32r*iD2, L32i = t32i*iD2;
  float Dv3 = Ad3 + no_f - (L30r*L30r + L30i*L30i)*Dv0 - (L31r*L31r + L31i*L31i)*Dv1
                        - (L32r*L32r + L32i*L32i)*Dv2;
  float iD3 = 1.0f / Dv3;

  // --- solve A z = w  (forward, scale, backward) ---
  float c0r = w0r, c0i = w0i;
  float c1r = w1r - (L10r*c0r - L10i*c0i);
  float c1i = w1i - (L10r*c0i + L10i*c0r);
  float c2r = w2r - (L20r*c0r - L20i*c0i) - (L21r*c1r - L21i*c1i);
  float c2i = w2i - (L20r*c0i + L20i*c0r) - (L21r*c1i + L21i*c1r);
  float c3r = w3r - (L30r*c0r - L30i*c0i) - (L31r*c1r - L31i*c1i) - (L32r*c2r - L32i*c2i);
  float c3i = w3i - (L30r*c0i + L30i*c0r) - (L31r*c1i + L31i*c1r) - (L32r*c2i + L32i*c2r);
  c0r *= iD0; c0i *= iD0;
  c1r *= iD1; c1i *= iD1;
  c2r *= iD2; c2i *= iD2;
  c3r *= iD3; c3i *= iD3;
  float z3r = c3r, z3i = c3i;
  float z2r = c2r - (L32r*z3r + L32i*z3i);
  float z2i = c2i - (L32r*z3i - L32i*z3r);
  float z1r = c1r - (L21r*z2r + L21i*z2i) - (L31r*z3r + L31i*z3i);
  float z1i = c1i - (L21r*z2i - L21i*z2r) - (L31r*z3i - L31i*z3r);
  float z0r = c0r - (L10r*z1r + L10i*z1i) - (L20r*z2r + L20i*z2i) - (L30r*z3r + L30i*z3i);
  float z0i = c0i - (L10r*z1i - L10i*z1r) - (L20r*z2i - L20i*z2r) - (L30r*z3i - L30i*z3r);

  // --- diag(A^-1) via M = L^-1 (unit lower):  Ainv_ss = sum_k |M[k][s]|^2 / D_k ---
  float M10r = -L10r, M10i = -L10i;
  float M21r = -L21r, M21i = -L21i;
  float M32r = -L32r, M32i = -L32i;
  float M20r = -L20r - (L21r*M10r - L21i*M10i);
  float M20i = -L20i - (L21r*M10i + L21i*M10r);
  float M31r = -L31r - (L32r*M21r - L32i*M21i);
  float M31i = -L31i - (L32r*M21i + L32i*M21r);
  float M30r = -L30r - (L31r*M10r - L31i*M10i) - (L32r*M20r - L32i*M20i);
  float M30i = -L30i - (L31r*M10i + L31i*M10r) - (L32r*M20i + L32i*M20r);
  float Ai0 = iD0 + (M10r*M10r + M10i*M10i)*iD1 + (M20r*M20r + M20i*M20i)*iD2
                  + (M30r*M30r + M30i*M30i)*iD3;
  float Ai1 = iD1 + (M21r*M21r + M21i*M21i)*iD2 + (M31r*M31r + M31i*M31i)*iD3;
  float Ai2 = iD2 + (M32r*M32r + M32i*M32i)*iD3;
  float Ai3 = iD3;

  float zrv[4] = {z0r, z1r, z2r, z3r};
  float ziv[4] = {z0i, z1i, z2i, z3i};
  float Aiv[4] = {Ai0, Ai1, Ai2, Ai3};

  // --- LLRs (store L = -llr, overlaid on d_out as floats) ---
#pragma unroll
  for (int s = 0; s < S_; ++s) {
    float dgg = 1.0f - no_f * Aiv[s];
    float dg = fminf(fmaxf(dgg, 1e-6f), (float)(1.0 - 1e-6));
    float xhr = zrv[s] / dg;
    float xhi = ziv[s] / dg;
    float noe = (1.0f - dg) / dg;
    float sc = -2.8284270763397217f / noe;  // -2*float32(sqrt(2)) / no_eff
    float2 o;
    o.x = -(sc * xhr);
    o.y = -(sc * xhi);
    size_t w = (size_t)(b * S_ + s);
    if (k2 < K_) {
      *reinterpret_cast<float2*>(outf + w * K_ + k2) = o;
    } else {
      *reinterpret_cast<float2*>(outf + (size_t)BSK + w * K_ + (k2 - K_)) = o;
    }
  }
}

__global__ __launch_bounds__(256) void bp_kernel(const int* __restrict__ bbits,
                                                 int* __restrict__ out) {
#pragma clang fp contract(off)
  __shared__ float Ls[NCODE];
  __shared__ float tot[NCODE];
  __shared__ float c2v[4][K_];
  int w = blockIdx.x;
  int tid = threadIdx.x;
  const float* outf = (const float*)out;

  // vectorized L load (912/4 = 228 float4 per half)
  if (tid < K_ / 4) {
    reinterpret_cast<float4*>(Ls)[tid] =
        reinterpret_cast<const float4*>(outf + (size_t)w * K_)[tid];
    reinterpret_cast<float4*>(Ls + K_)[tid] =
        reinterpret_cast<const float4*>(outf + (size_t)BSK + (size_t)w * K_)[tid];
  }
  for (int n = tid; n < K_; n += 256) {
    c2v[0][n] = 0.f; c2v[1][n] = 0.f; c2v[2][n] = 0.f; c2v[3][n] = 0.f;
  }
  __syncthreads();

  for (int it = 0; it < BP_ITERS; ++it) {
    // phase A: tot[n] = L[n] + sum of incident c2v (gather form)
    for (int n = tid; n < K_; n += 256) {
      int ca = n + 7;   if (ca >= K_) ca -= K_;
      int cb = n + 150; if (cb >= K_) cb -= K_;
      float e = c2v[0][n] + c2v[1][ca] + c2v[2][cb];
      tot[n] = Ls[n] + e;
    }
    for (int n = tid; n < K_; n += 256) {
      tot[K_ + n] = Ls[K_ + n] + c2v[3][n];
    }
    __syncthreads();
    // phase B: per-check min-sum update
    for (int c = tid; c < K_; c += 256) {
      int v1 = c - 7;   if (v1 < 0) v1 += K_;
      int v2 = c - 150; if (v2 < 0) v2 += K_;
      float m0 = tot[c]       - c2v[0][c];
      float m1 = tot[v1]      - c2v[1][c];
      float m2 = tot[v2]      - c2v[2][c];
      float m3 = tot[K_ + c]  - c2v[3][c];
      float a0 = fabsf(m0), a1 = fabsf(m1), a2 = fabsf(m2), a3 = fabsf(m3);
      float min1 = a0, min2 = __builtin_inff();
      int am = 0;
      if (a1 < min1) { min2 = min1; min1 = a1; am = 1; } else if (a1 < min2) min2 = a1;
      if (a2 < min1) { min2 = min1; min1 = a2; am = 2; } else if (a2 < min2) min2 = a2;
      if (a3 < min1) { min2 = min1; min1 = a3; am = 3; } else if (a3 < min2) min2 = a3;
      float s0 = (m0 < 0.f) ? -1.f : 1.f;
      float s1 = (m1 < 0.f) ? -1.f : 1.f;
      float s2 = (m2 < 0.f) ? -1.f : 1.f;
      float s3 = (m3 < 0.f) ? -1.f : 1.f;
      float sp = s0 * s1 * s2 * s3;
      c2v[0][c] = (sp * s0) * ((am == 0) ? min2 : min1);
      c2v[1][c] = (sp * s1) * ((am == 1) ? min2 : min1);
      c2v[2][c] = (sp * s2) * ((am == 2) ? min2 : min1);
      c2v[3][c] = (sp * s3) * ((am == 3) ? min2 : min1);
    }
    __syncthreads();
  }

  // final: hard decisions on info bits + copy b_bits to first half
  for (int k = tid; k < K_; k += 256) {
    int ca = k + 7;   if (ca >= K_) ca -= K_;
    int cb = k + 150; if (cb >= K_) cb -= K_;
    float ttt = Ls[k] + c2v[0][k] + c2v[1][ca] + c2v[2][cb];
    out[(size_t)BSK + (size_t)w * K_ + k] = (ttt < 0.f) ? 1 : 0;
    out[(size_t)w * K_ + k] = bbits[(size_t)w * K_ + k];
  }
}

extern "C" void kernel_launch(void* const* d_in, const int* in_sizes, int n_in,
                              void* d_out, int out_size, void* d_ws, size_t ws_size,
                              hipStream_t stream) {
  const int*   b_bits = (const int*)d_in[0];
  const float* h_real = (const float*)d_in[1];
  const float* h_imag = (const float*)d_in[2];
  const float* n_real = (const float*)d_in[3];
  const float* n_imag = (const float*)d_in[4];
  const int*   ebno   = (const int*)d_in[5];
  int* out = (int*)d_out;
  float* cst = (float*)d_ws;

  setup_kernel<<<1, 1, 0, stream>>>(ebno, cst);
  mmse_llr_kernel<<<(B_ * D_ + 255) / 256, 256, 0, stream>>>(
      b_bits, h_real, h_imag, n_real, n_imag, cst, (float*)d_out);
  bp_kernel<<<B_ * S_, 256, 0, stream>>>(b_bits, out);
}

// Round 3
// 67.924 us; speedup vs baseline: 2.2818x; 1.4128x over previous
//
#include <hip/hip_runtime.h>

#define B_ 512
#define S_ 4
#define K_ 912
#define R_ 8
#define D_ 912
#define NCODE 1824
#define BSK (B_*S_*K_)   /* 1867776 */
#define BP_ITERS 10
#define NTH 228          /* 4*228 = 912 */

// one-thread kernel: compute no / noise-scale once (fp64 pow off the hot path)
__global__ void setup_kernel(const int* __restrict__ ebno, float* __restrict__ cst) {
  int ei = ebno[0];
  float ef = (ei >= -100 && ei <= 100) ? (float)ei : __int_as_float(ei);
  double no_d = pow(10.0, -(double)ef / 10.0);
  cst[0] = (float)no_d;
  cst[1] = (float)sqrt(no_d * 0.5);
}

__global__ __launch_bounds__(256) void mmse_llr_kernel(
    const int* __restrict__ bbits, const float* __restrict__ hre,
    const float* __restrict__ him, const float* __restrict__ nre,
    const float* __restrict__ nim, const float* __restrict__ cst,
    float* __restrict__ outf) {
#pragma clang fp contract(off)
  __shared__ float4 shre[1024];  // 16 KB: one r-half of h_real for 256 threads
  __shared__ float4 shim[1024];  // 16 KB
  int tid = threadIdx.x;
  int t0 = blockIdx.x * 256;
  int t = t0 + tid;
  int b = t / D_;
  int d = t - b * D_;

  const float no_f = cst[0];
  const float nscale = cst[1];
  const float INV2 = 0.70710678118654752440f;

  // --- QPSK symbols for the 4 streams at subcarrier d ---
  float xr[S_], xq[S_];
  int k2 = 2 * d;
#pragma unroll
  for (int s = 0; s < S_; ++s) {
    const int* bb = bbits + (b * S_ + s) * K_;
    int c0, c1;
    if (k2 < K_) {
      c0 = bb[k2];
      c1 = bb[k2 + 1];
    } else {
      int j0 = k2 - K_, j1 = k2 + 1 - K_;
      int j0a = j0 - 7;   if (j0a < 0) j0a += K_;
      int j0b = j0 - 150; if (j0b < 0) j0b += K_;
      c0 = (bb[j0] + bb[j0a] + bb[j0b]) & 1;
      int j1a = j1 - 7;   if (j1a < 0) j1a += K_;
      int j1b = j1 - 150; if (j1b < 0) j1b += K_;
      c1 = (bb[j1] + bb[j1a] + bb[j1b]) & 1;
    }
    xr[s] = (1.0f - 2.0f * (float)c0) * INV2;
    xq[s] = (1.0f - 2.0f * (float)c1) * INV2;
  }

  // --- noise (direct, small) ---
  const float4* nr4 = reinterpret_cast<const float4*>(nre + (size_t)t * 8);
  const float4* ni4 = reinterpret_cast<const float4*>(nim + (size_t)t * 8);
  float nrv[8], niv[8];
  {
    float4 a = nr4[0], b2 = nr4[1];
    nrv[0]=a.x; nrv[1]=a.y; nrv[2]=a.z; nrv[3]=a.w;
    nrv[4]=b2.x; nrv[5]=b2.y; nrv[6]=b2.z; nrv[7]=b2.w;
    float4 c = ni4[0], d2 = ni4[1];
    niv[0]=c.x; niv[1]=c.y; niv[2]=c.z; niv[3]=c.w;
    niv[4]=d2.x; niv[5]=d2.y; niv[6]=d2.z; niv[7]=d2.w;
  }

  const float4* hre4 = reinterpret_cast<const float4*>(hre);
  const float4* him4 = reinterpret_cast<const float4*>(him);

  float Ad0=0.f, Ad1=0.f, Ad2=0.f, Ad3=0.f;
  float A10r=0.f,A10i=0.f,A20r=0.f,A20i=0.f,A21r=0.f,A21i=0.f;
  float A30r=0.f,A30i=0.f,A31r=0.f,A31i=0.f,A32r=0.f,A32i=0.f;
  float w0r=0.f,w0i=0.f,w1r=0.f,w1i=0.f,w2r=0.f,w2i=0.f,w3r=0.f,w3i=0.f;

#pragma unroll
  for (int half = 0; half < 2; ++half) {
    if (half) __syncthreads();  // previous-half readers must finish
    // --- stage this r-half, coalesced global -> swizzled LDS ---
#pragma unroll
    for (int j = 0; j < 4; ++j) {
      int m = j * 256 + tid;
      int T = m >> 2, q = m & 3;
      size_t gidx = (size_t)(t0 + T) * 8 + half * 4 + q;
      float4 vr = hre4[gidx];
      float4 vi = him4[gidx];
      int dst = T * 4 + (q ^ ((T >> 1) & 3));
      shre[dst] = vr;
      shim[dst] = vi;
    }
    __syncthreads();
#pragma unroll
    for (int rr = 0; rr < 4; ++rr) {
      int r = half * 4 + rr;
      int slot = rr ^ ((tid >> 1) & 3);
      float4 h4r = shre[tid * 4 + slot];
      float4 h4i = shim[tid * 4 + slot];
      float hr0=h4r.x*INV2, hr1=h4r.y*INV2, hr2=h4r.z*INV2, hr3=h4r.w*INV2;
      float hi0=h4i.x*INV2, hi1=h4i.y*INV2, hi2=h4i.z*INV2, hi3=h4i.w*INV2;
      float yr = 0.f, yi = 0.f;
      yr += hr0*xr[0] - hi0*xq[0]; yi += hr0*xq[0] + hi0*xr[0];
      yr += hr1*xr[1] - hi1*xq[1]; yi += hr1*xq[1] + hi1*xr[1];
      yr += hr2*xr[2] - hi2*xq[2]; yi += hr2*xq[2] + hi2*xr[2];
      yr += hr3*xr[3] - hi3*xq[3]; yi += hr3*xq[3] + hi3*xr[3];
      yr += nrv[r]*nscale; yi += niv[r]*nscale;
      Ad0 += hr0*hr0 + hi0*hi0;
      Ad1 += hr1*hr1 + hi1*hi1;
      Ad2 += hr2*hr2 + hi2*hi2;
      Ad3 += hr3*hr3 + hi3*hi3;
      A10r += hr1*hr0 + hi1*hi0;  A10i += hr1*hi0 - hi1*hr0;
      A20r += hr2*hr0 + hi2*hi0;  A20i += hr2*hi0 - hi2*hr0;
      A21r += hr2*hr1 + hi2*hi1;  A21i += hr2*hi1 - hi2*hr1;
      A30r += hr3*hr0 + hi3*hi0;  A30i += hr3*hi0 - hi3*hr0;
      A31r += hr3*hr1 + hi3*hi1;  A31i += hr3*hi1 - hi3*hr1;
      A32r += hr3*hr2 + hi3*hi2;  A32i += hr3*hi2 - hi3*hr2;
      w0r += hr0*yr + hi0*yi;  w0i += hr0*yi - hi0*yr;
      w1r += hr1*yr + hi1*yi;  w1i += hr1*yi - hi1*yr;
      w2r += hr2*yr + hi2*yi;  w2i += hr2*yi - hi2*yr;
      w3r += hr3*yr + hi3*yi;  w3i += hr3*yi - hi3*yr;
    }
  }

  // --- LDL^H factorization (A is HPD) ---
  float Dv0 = Ad0 + no_f;
  float iD0 = 1.0f / Dv0;
  float L10r = A10r*iD0, L10i = A10i*iD0;
  float L20r = A20r*iD0, L20i = A20i*iD0;
  float L30r = A30r*iD0, L30i = A30i*iD0;
  float Dv1 = Ad1 + no_f - (L10r*L10r + L10i*L10i)*Dv0;
  float iD1 = 1.0f / Dv1;
  float t21r = A21r - (L20r*L10r + L20i*L10i)*Dv0;
  float t21i = A21i - (L20i*L10r - L20r*L10i)*Dv0;
  float L21r = t21r*iD1, L21i = t21i*iD1;
  float t31r = A31r - (L30r*L10r + L30i*L10i)*Dv0;
  float t31i = A31i - (L30i*L10r - L30r*L10i)*Dv0;
  float L31r = t31r*iD1, L31i = t31i*iD1;
  float Dv2 = Ad2 + no_f - (L20r*L20r + L20i*L20i)*Dv0 - (L21r*L21r + L21i*L21i)*Dv1;
  float iD2 = 1.0f / Dv2;
  float t32r = A32r - (L30r*L20r + L30i*L20i)*Dv0 - (L31r*L21r + L31i*L21i)*Dv1;
  float t32i = A32i - (L30i*L20r - L30r*L20i)*Dv0 - (L31i*L21r - L31r*L21i)*Dv1;
  float L32r = t32r*iD2, L32i = t32i*iD2;
  float Dv3 = Ad3 + no_f - (L30r*L30r + L30i*L30i)*Dv0 - (L31r*L31r + L31i*L31i)*Dv1
                        - (L32r*L32r + L32i*L32i)*Dv2;
  float iD3 = 1.0f / Dv3;

  // --- solve A z = w ---
  float c0r = w0r, c0i = w0i;
  float c1r = w1r - (L10r*c0r - L10i*c0i);
  float c1i = w1i - (L10r*c0i + L10i*c0r);
  float c2r = w2r - (L20r*c0r - L20i*c0i) - (L21r*c1r - L21i*c1i);
  float c2i = w2i - (L20r*c0i + L20i*c0r) - (L21r*c1i + L21i*c1r);
  float c3r = w3r - (L30r*c0r - L30i*c0i) - (L31r*c1r - L31i*c1i) - (L32r*c2r - L32i*c2i);
  float c3i = w3i - (L30r*c0i + L30i*c0r) - (L31r*c1i + L31i*c1r) - (L32r*c2i + L32i*c2r);
  c0r *= iD0; c0i *= iD0;
  c1r *= iD1; c1i *= iD1;
  c2r *= iD2; c2i *= iD2;
  c3r *= iD3; c3i *= iD3;
  float z3r = c3r, z3i = c3i;
  float z2r = c2r - (L32r*z3r + L32i*z3i);
  float z2i = c2i - (L32r*z3i - L32i*z3r);
  float z1r = c1r - (L21r*z2r + L21i*z2i) - (L31r*z3r + L31i*z3i);
  float z1i = c1i - (L21r*z2i - L21i*z2r) - (L31r*z3i - L31i*z3r);
  float z0r = c0r - (L10r*z1r + L10i*z1i) - (L20r*z2r + L20i*z2i) - (L30r*z3r + L30i*z3i);
  float z0i = c0i - (L10r*z1i - L10i*z1r) - (L20r*z2i - L20i*z2r) - (L30r*z3i - L30i*z3r);

  // --- diag(A^-1) via M = L^-1 ---
  float M10r = -L10r, M10i = -L10i;
  float M21r = -L21r, M21i = -L21i;
  float M32r = -L32r, M32i = -L32i;
  float M20r = -L20r - (L21r*M10r - L21i*M10i);
  float M20i = -L20i - (L21r*M10i + L21i*M10r);
  float M31r = -L31r - (L32r*M21r - L32i*M21i);
  float M31i = -L31i - (L32r*M21i + L32i*M21r);
  float M30r = -L30r - (L31r*M10r - L31i*M10i) - (L32r*M20r - L32i*M20i);
  float M30i = -L30i - (L31r*M10i + L31i*M10r) - (L32r*M20i + L32i*M20r);
  float Ai0 = iD0 + (M10r*M10r + M10i*M10i)*iD1 + (M20r*M20r + M20i*M20i)*iD2
                  + (M30r*M30r + M30i*M30i)*iD3;
  float Ai1 = iD1 + (M21r*M21r + M21i*M21i)*iD2 + (M31r*M31r + M31i*M31i)*iD3;
  float Ai2 = iD2 + (M32r*M32r + M32i*M32i)*iD3;
  float Ai3 = iD3;

  float zrv[4] = {z0r, z1r, z2r, z3r};
  float ziv[4] = {z0i, z1i, z2i, z3i};
  float Aiv[4] = {Ai0, Ai1, Ai2, Ai3};

#pragma unroll
  for (int s = 0; s < S_; ++s) {
    float dgg = 1.0f - no_f * Aiv[s];
    float dg = fminf(fmaxf(dgg, 1e-6f), (float)(1.0 - 1e-6));
    float xhr = zrv[s] / dg;
    float xhi = ziv[s] / dg;
    float noe = (1.0f - dg) / dg;
    float sc = -2.8284270763397217f / noe;
    float2 o;
    o.x = -(sc * xhr);
    o.y = -(sc * xhi);
    size_t w = (size_t)(b * S_ + s);
    if (k2 < K_) {
      *reinterpret_cast<float2*>(outf + w * K_ + k2) = o;
    } else {
      *reinterpret_cast<float2*>(outf + (size_t)BSK + w * K_ + (k2 - K_)) = o;
    }
  }
}

__global__ __launch_bounds__(256) void bp_kernel(const int* __restrict__ bbits,
                                                 int* __restrict__ out) {
#pragma clang fp contract(off)
  __shared__ float tot[K_];
  __shared__ float E0[K_];  // E0[n] = c2v slot-0 of check n
  __shared__ float E1[K_];  // E1[n] = c2v slot-1 of check (n+7)%K
  __shared__ float E2[K_];  // E2[n] = c2v slot-2 of check (n+150)%K
  int w = blockIdx.x;
  int tid = threadIdx.x;
  const float* outf = (const float*)out;
  bool act = tid < NTH;

  float Lv[4], LP[4];
  float c0v[4] = {0.f,0.f,0.f,0.f};
  float c1v[4] = {0.f,0.f,0.f,0.f};
  float c2v_[4] = {0.f,0.f,0.f,0.f};
  float c3v[4] = {0.f,0.f,0.f,0.f};

  if (act) {
#pragma unroll
    for (int k = 0; k < 4; ++k) {
      int n = tid + NTH * k;
      Lv[k] = outf[(size_t)w * K_ + n];
      LP[k] = outf[(size_t)BSK + (size_t)w * K_ + n];
      E0[n] = 0.f; E1[n] = 0.f; E2[n] = 0.f;
    }
  }
  __syncthreads();

  for (int it = 0; it < BP_ITERS; ++it) {
    // phase A: tot[n] = L[n] + ((E0+E1)+E2)   (matches reference scatter order)
    if (act) {
#pragma unroll
      for (int k = 0; k < 4; ++k) {
        int n = tid + NTH * k;
        tot[n] = Lv[k] + ((E0[n] + E1[n]) + E2[n]);
      }
    }
    __syncthreads();
    // phase B: per-check min-sum, c2v in registers, write shifted E arrays
    if (act) {
#pragma unroll
      for (int k = 0; k < 4; ++k) {
        int c = tid + NTH * k;
        int i1 = c - 7;   if (i1 < 0) i1 += K_;
        int i2 = c - 150; if (i2 < 0) i2 += K_;
        float m0 = tot[c]  - c0v[k];
        float m1 = tot[i1] - c1v[k];
        float m2 = tot[i2] - c2v_[k];
        float totP = LP[k] + c3v[k];      // keep exact reference rounding
        float m3 = totP - c3v[k];
        float a0 = fabsf(m0), a1 = fabsf(m1), a2 = fabsf(m2), a3 = fabsf(m3);
        float t01 = fminf(a0, a1), t23 = fminf(a2, a3);
        float e0 = fminf(a1, t23);
        float e1 = fminf(a0, t23);
        float e2 = fminf(t01, a3);
        float e3 = fminf(t01, a2);
        unsigned s0 = __float_as_uint(m0) & 0x80000000u;
        unsigned s1 = __float_as_uint(m1) & 0x80000000u;
        unsigned s2 = __float_as_uint(m2) & 0x80000000u;
        unsigned s3 = __float_as_uint(m3) & 0x80000000u;
        unsigned sp = (s0 ^ s1) ^ (s2 ^ s3);
        float n0 = __uint_as_float(__float_as_uint(e0) ^ (sp ^ s0));
        float n1 = __uint_as_float(__float_as_uint(e1) ^ (sp ^ s1));
        float n2 = __uint_as_float(__float_as_uint(e2) ^ (sp ^ s2));
        float n3 = __uint_as_float(__float_as_uint(e3) ^ (sp ^ s3));
        c0v[k] = n0; c1v[k] = n1; c2v_[k] = n2; c3v[k] = n3;
        E0[c] = n0; E1[i1] = n1; E2[i2] = n2;
      }
    }
    __syncthreads();
  }

  // final: hard decisions + b_bits copy
  if (act) {
#pragma unroll
    for (int k = 0; k < 4; ++k) {
      int n = tid + NTH * k;
      float ttt = Lv[k] + ((E0[n] + E1[n]) + E2[n]);
      out[(size_t)BSK + (size_t)w * K_ + n] = (ttt < 0.f) ? 1 : 0;
      out[(size_t)w * K_ + n] = bbits[(size_t)w * K_ + n];
    }
  }
}

extern "C" void kernel_launch(void* const* d_in, const int* in_sizes, int n_in,
                              void* d_out, int out_size, void* d_ws, size_t ws_size,
                              hipStream_t stream) {
  const int*   b_bits = (const int*)d_in[0];
  const float* h_real = (const float*)d_in[1];
  const float* h_imag = (const float*)d_in[2];
  const float* n_real = (const float*)d_in[3];
  const float* n_imag = (const float*)d_in[4];
  const int*   ebno   = (const int*)d_in[5];
  int* out = (int*)d_out;
  float* cst = (float*)d_ws;

  setup_kernel<<<1, 1, 0, stream>>>(ebno, cst);
  mmse_llr_kernel<<<(B_ * D_) / 256, 256, 0, stream>>>(
      b_bits, h_real, h_imag, n_real, n_imag, cst, (float*)d_out);
  bp_kernel<<<B_ * S_, 256, 0, stream>>>(b_bits, out);
}